// Round 11
// baseline (172.206 us; speedup 1.0000x reference)
//
#include <hip/hip_runtime.h>
#include <hip/hip_fp16.h>
#include <hip/hip_cooperative_groups.h>

// GCN 2-layer forward — f16 CSR-gather fused with MFMA MLP.
// R11: entire CSR build + prescale collapsed into ONE cooperative kernel
// (edges stay in registers across hist->bin; grid.sync between phases).
// k_agg_mlp: 32 nodes/block; phase1 gather (8 rows in flight per group) ->
// swizzled LDS f16 rows; phase2 waves 0-1 run 16x16x32_f16 MFMA tiles.
// k_out: scalar CSR gather of svs.

#define NNODES 100000
#define INF 64
#define HID 128
#define MAXBK 128     // max buckets (1024 nodes each)
#define TILE_E 16384  // edges per tile (1024 thr x 16)

namespace cg = cooperative_groups;

using half8 = __attribute__((ext_vector_type(8))) _Float16;
using f32x4 = __attribute__((ext_vector_type(4))) float;

// One cooperative kernel: phases
//  A (block=tile): load 16 edges/thread to regs, LDS hist -> tileCnt
//  B (block 0):    bucket-major scan -> tileBase, bBase, rowPtr[n]
//  C (block=tile): bin from regs -> binned (dense per-(tile,bucket) runs)
//  D (block=bucket): per-bucket counting sort -> rowPtr, dinv, eSrc
//  E (grid-stride): Xs = f16(dinv*X); W1t = f16(W1^T)
__global__ __launch_bounds__(1024, 1) void k_build(
        const int* __restrict__ srcA, const int* __restrict__ dstA,
        const float4* __restrict__ X4, const float* __restrict__ W1,
        int* __restrict__ tileCnt, int* __restrict__ tileBase,
        int* __restrict__ bBase, int* __restrict__ rowPtr,
        float* __restrict__ dinv, unsigned* __restrict__ binned,
        int* __restrict__ eSrc, uint4* __restrict__ Xs4,
        _Float16* __restrict__ W1t, int n, int nE, int nt, int nbk) {
    cg::grid_group grid = cg::this_grid();
    __shared__ int lds[1024];
    __shared__ int lds2[1024];
    int tid = threadIdx.x;
    int bx = blockIdx.x;

    int dreg[16], sreg[16];
    // ---- phase A: histogram (edges -> registers) ----
    if (bx < nt) {
        if (tid < MAXBK) lds[tid] = 0;
        __syncthreads();
        int base = bx * TILE_E;
#pragma unroll
        for (int k = 0; k < 16; ++k) {
            int e = base + k * 1024 + tid;
            if (e < nE) {
                dreg[k] = dstA[e];
                sreg[k] = srcA[e];
                atomicAdd(&lds[((unsigned)dreg[k]) >> 10], 1);
            } else {
                dreg[k] = -1;
            }
        }
        __syncthreads();
        if (tid < MAXBK) tileCnt[bx * MAXBK + tid] = lds[tid];
    }
    grid.sync();

    // ---- phase B: scan (block 0) ----
    if (bx == 0) {
        int b = tid & (MAXBK - 1);
        int tg = tid >> 7;  // 0..7
        int cpg = (nt + 7) / 8;
        int tlo = tg * cpg, thi = min(tlo + cpg, nt);
        int sum = 0;
        for (int t = tlo; t < thi; ++t) sum += tileCnt[t * MAXBK + b];
        lds[tg * MAXBK + b] = sum;
        __syncthreads();
        int coff = 0;
        for (int g = 0; g < tg; ++g) coff += lds[g * MAXBK + b];
        int ctot = 0;
#pragma unroll
        for (int g = 0; g < 8; ++g) ctot += lds[g * MAXBK + b];
        if (tg == 0) lds2[b] = ctot;
        __syncthreads();
        for (int off = 1; off < MAXBK; off <<= 1) {
            int u = (tg == 0 && b >= off) ? lds2[b - off] : 0;
            __syncthreads();
            if (tg == 0) lds2[b] += u;
            __syncthreads();
        }
        int colBase = lds2[b] - ctot;
        if (tg == 0 && b < nbk) bBase[b] = colBase;
        if (tg == 0 && b == nbk - 1) { bBase[nbk] = lds2[b]; rowPtr[n] = lds2[b]; }
        int run = colBase + coff;
        for (int t = tlo; t < thi; ++t) {
            tileBase[t * MAXBK + b] = run;
            run += tileCnt[t * MAXBK + b];
        }
    }
    grid.sync();

    // ---- phase C: binning from registers ----
    if (bx < nt) {
        if (tid < MAXBK) {
            lds[tid] = tileBase[bx * MAXBK + tid];
            lds2[tid] = 0;
        }
        __syncthreads();
#pragma unroll
        for (int k = 0; k < 16; ++k) {
            if (dreg[k] >= 0) {
                int bk = ((unsigned)dreg[k]) >> 10;
                int off = atomicAdd(&lds2[bk], 1);
                binned[lds[bk] + off] =
                    ((unsigned)(dreg[k] & 1023) << 17) | (unsigned)sreg[k];
            }
        }
    }
    grid.sync();

    // ---- phase D: per-bucket counting sort ----
    if (bx < nbk) {
        int lo = bBase[bx], hi = bBase[bx + 1];
        lds[tid] = 0;
        __syncthreads();
        for (int i = lo + tid; i < hi; i += 1024)
            atomicAdd(&lds[binned[i] >> 17], 1);
        __syncthreads();
        int own = lds[tid];
        for (int off = 1; off < 1024; off <<= 1) {
            int u = (tid >= off) ? lds[tid - off] : 0;
            __syncthreads();
            lds[tid] += u;
            __syncthreads();
        }
        int pos0 = lo + lds[tid] - own;
        lds2[tid] = pos0;
        int node = (bx << 10) + tid;
        if (node < n) {
            rowPtr[node] = pos0;
            dinv[node] = rsqrtf((float)(own + 1));  // +1 self loop
        }
        __syncthreads();
        for (int i = lo + tid; i < hi; i += 1024) {
            unsigned v = binned[i];
            int pos = atomicAdd(&lds2[v >> 17], 1);
            eSrc[pos] = (int)(v & 0x1FFFFu);
        }
    }
    grid.sync();

    // ---- phase E: prescale + W1 transpose (grid-stride) ----
    int stride = gridDim.x * 1024;
    int totalE = n * 8 + HID * INF;
    for (int t = bx * 1024 + tid; t < totalE; t += stride) {
        if (t < n * 8) {
            int node = t >> 3;
            int r = t & 7;
            float dD = dinv[node];
            float4 a = X4[(size_t)node * 16 + r * 2];
            float4 b = X4[(size_t)node * 16 + r * 2 + 1];
            __half2 h0 = __float22half2_rn(make_float2(dD * a.x, dD * a.y));
            __half2 h1 = __float22half2_rn(make_float2(dD * a.z, dD * a.w));
            __half2 h2 = __float22half2_rn(make_float2(dD * b.x, dD * b.y));
            __half2 h3 = __float22half2_rn(make_float2(dD * b.z, dD * b.w));
            uint4 o;
            o.x = *(unsigned*)&h0; o.y = *(unsigned*)&h1;
            o.z = *(unsigned*)&h2; o.w = *(unsigned*)&h3;
            Xs4[t] = o;
        } else {
            int i = t - n * 8;
            int nCol = i >> 6;   // 0..127
            int k = i & 63;
            W1t[i] = (_Float16)W1[k * HID + nCol];
        }
    }
}

__device__ inline void acc8_add(const uint4& v, float* acc) {
    const __half2* hp = (const __half2*)&v;
#pragma unroll
    for (int i = 0; i < 4; ++i) {
        float2 f = __half22float2(hp[i]);
        acc[2 * i]     += f.x;
        acc[2 * i + 1] += f.y;
    }
}

// Fused gather + MFMA MLP. 256 thr = 32 nodes/block.
// Phase 1: 8 lanes/node gather agg row (f32 acc, 8 rows in flight) ->
//          f16 row in swizzled LDS.
// Phase 2: waves 0-1 each run one 16-node MFMA tile (8 N-tiles x 2 K-steps),
//          A/B frags from LDS; epilogue bias+relu+W2-dot; svs = dinv*result.
__global__ __launch_bounds__(256) void k_agg_mlp(const uint4* __restrict__ Xs4,
                                                 const int* __restrict__ rowPtr,
                                                 const int* __restrict__ eSrc,
                                                 const float* __restrict__ dinv,
                                                 const uint4* __restrict__ W1t4,
                                                 const float* __restrict__ b1,
                                                 const float* __restrict__ W2,
                                                 float* __restrict__ svs, int n) {
    __shared__ __align__(16) unsigned short W1s[HID * INF];  // 16 KB swizzled
    __shared__ __align__(16) unsigned short aggS[32 * INF];  // 4 KB swizzled
    __shared__ float b1s[HID];
    __shared__ float W2s[HID];
    int tid = threadIdx.x;

    // phase 0: stage W1t into swizzled LDS (+ bias/W2)
    for (int i = tid; i < HID * 8; i += 256) {   // 1024 uint4 chunks
        int c = i >> 3, cb = i & 7;
        uint4 v = W1t4[i];
        int off = c * 128 + ((cb * 16) ^ ((c & 7) << 4));
        *(uint4*)((char*)W1s + off) = v;
    }
    if (tid < HID) {
        b1s[tid] = b1[tid];
        W2s[tid] = W2[tid];
    }

    // phase 1: gather
    int node0 = blockIdx.x * 32;
    int w = tid >> 3;   // local node 0..31
    int r = tid & 7;    // 16B chunk of the 128B row
    int node = node0 + w;
    if (node < n) {
        int beg = rowPtr[node];
        int end = rowPtr[node + 1];
        float dD = dinv[node];
        float acc[8];
        {   // self-loop init
            uint4 v = Xs4[(size_t)node * 8 + r];
            const __half2* hp = (const __half2*)&v;
#pragma unroll
            for (int i = 0; i < 4; ++i) {
                float2 f = __half22float2(hp[i]);
                acc[2 * i] = f.x;
                acc[2 * i + 1] = f.y;
            }
        }
        int j = beg;
        int aEnd = min(end, (beg + 3) & ~3);
        for (; j < aEnd; ++j) {
            uint4 v = Xs4[(size_t)eSrc[j] * 8 + r];
            acc8_add(v, acc);
        }
        for (; j + 7 < end; j += 8) {   // 8 rows in flight
            int4 sa = *(const int4*)(eSrc + j);
            int4 sb = *(const int4*)(eSrc + j + 4);
            uint4 v0 = Xs4[(size_t)sa.x * 8 + r];
            uint4 v1 = Xs4[(size_t)sa.y * 8 + r];
            uint4 v2 = Xs4[(size_t)sa.z * 8 + r];
            uint4 v3 = Xs4[(size_t)sa.w * 8 + r];
            uint4 v4 = Xs4[(size_t)sb.x * 8 + r];
            uint4 v5 = Xs4[(size_t)sb.y * 8 + r];
            uint4 v6 = Xs4[(size_t)sb.z * 8 + r];
            uint4 v7 = Xs4[(size_t)sb.w * 8 + r];
            acc8_add(v0, acc); acc8_add(v1, acc); acc8_add(v2, acc); acc8_add(v3, acc);
            acc8_add(v4, acc); acc8_add(v5, acc); acc8_add(v6, acc); acc8_add(v7, acc);
        }
        if (j + 3 < end) {
            int4 s4 = *(const int4*)(eSrc + j);
            uint4 v0 = Xs4[(size_t)s4.x * 8 + r];
            uint4 v1 = Xs4[(size_t)s4.y * 8 + r];
            uint4 v2 = Xs4[(size_t)s4.z * 8 + r];
            uint4 v3 = Xs4[(size_t)s4.w * 8 + r];
            acc8_add(v0, acc); acc8_add(v1, acc); acc8_add(v2, acc); acc8_add(v3, acc);
            j += 4;
        }
        for (; j < end; ++j) {
            uint4 v = Xs4[(size_t)eSrc[j] * 8 + r];
            acc8_add(v, acc);
        }
        __half2 h0 = __float22half2_rn(make_float2(dD * acc[0], dD * acc[1]));
        __half2 h1 = __float22half2_rn(make_float2(dD * acc[2], dD * acc[3]));
        __half2 h2 = __float22half2_rn(make_float2(dD * acc[4], dD * acc[5]));
        __half2 h3 = __float22half2_rn(make_float2(dD * acc[6], dD * acc[7]));
        uint4 o;
        o.x = *(unsigned*)&h0; o.y = *(unsigned*)&h1;
        o.z = *(unsigned*)&h2; o.w = *(unsigned*)&h3;
        int off = w * 128 + ((r * 16) ^ ((w & 7) << 4));
        *(uint4*)((char*)aggS + off) = o;
    }
    __syncthreads();

    // phase 2: MFMA (waves 0-1)
    int wave = tid >> 6;
    if (wave < 2) {
        int l = tid & 63;
        int row16 = l & 15;
        int kg = l >> 4;
        int lrow = wave * 16 + row16;
        int swzA = (lrow & 7) << 4;
        half8 a0 = *(const half8*)((const char*)aggS + lrow * 128 + ((kg * 16) ^ swzA));
        half8 a1 = *(const half8*)((const char*)aggS + lrow * 128 + ((64 + kg * 16) ^ swzA));
        float p0 = 0.0f, p1 = 0.0f, p2 = 0.0f, p3 = 0.0f;
#pragma unroll
        for (int nt = 0; nt < 8; ++nt) {
            int c = nt * 16 + row16;
            int swzB = (c & 7) << 4;
            half8 bf0 = *(const half8*)((const char*)W1s + c * 128 + ((kg * 16) ^ swzB));
            half8 bf1 = *(const half8*)((const char*)W1s + c * 128 + ((64 + kg * 16) ^ swzB));
            f32x4 acc4 = {0.0f, 0.0f, 0.0f, 0.0f};
            acc4 = __builtin_amdgcn_mfma_f32_16x16x32_f16(a0, bf0, acc4, 0, 0, 0);
            acc4 = __builtin_amdgcn_mfma_f32_16x16x32_f16(a1, bf1, acc4, 0, 0, 0);
            float b1v = b1s[c];
            float w2v = W2s[c];
            float h;
            h = fmaxf(acc4[0] + b1v, 0.0f); p0 = fmaf(h, w2v, p0);
            h = fmaxf(acc4[1] + b1v, 0.0f); p1 = fmaf(h, w2v, p1);
            h = fmaxf(acc4[2] + b1v, 0.0f); p2 = fmaf(h, w2v, p2);
            h = fmaxf(acc4[3] + b1v, 0.0f); p3 = fmaf(h, w2v, p3);
        }
#pragma unroll
        for (int off = 1; off < 16; off <<= 1) {
            p0 += __shfl_xor(p0, off, 64);
            p1 += __shfl_xor(p1, off, 64);
            p2 += __shfl_xor(p2, off, 64);
            p3 += __shfl_xor(p3, off, 64);
        }
        if (row16 == 0) {
            int nd = node0 + wave * 16 + kg * 4;
            if (nd + 0 < n) svs[nd + 0] = dinv[nd + 0] * p0;
            if (nd + 1 < n) svs[nd + 1] = dinv[nd + 1] * p1;
            if (nd + 2 < n) svs[nd + 2] = dinv[nd + 2] * p2;
            if (nd + 3 < n) svs[nd + 3] = dinv[nd + 3] * p3;
        }
    }
}

// 4 nodes per wave: out[d] = dD*(sum svs[src] + svs[d]) + b2
__global__ __launch_bounds__(256) void k_out(const int* __restrict__ rowPtr,
                                             const int* __restrict__ eSrc,
                                             const float* __restrict__ dinv,
                                             const float* __restrict__ svs,
                                             const float* __restrict__ b2,
                                             float* __restrict__ out, int n) {
    int t = blockIdx.x * blockDim.x + threadIdx.x;
    int node = t >> 4;
    int r = t & 15;
    if (node >= n) return;
    int beg = rowPtr[node];
    int end = rowPtr[node + 1];
    float p = 0.0f;
    for (int j = beg + r; j < end; j += 16) p += svs[eSrc[j]];
    p += __shfl_xor(p, 1, 16);
    p += __shfl_xor(p, 2, 16);
    p += __shfl_xor(p, 4, 16);
    p += __shfl_xor(p, 8, 16);
    if (r == 0) {
        float dD = dinv[node];
        out[node] = fmaf(dD, p + svs[node], b2[0]);
    }
}

extern "C" void kernel_launch(void* const* d_in, const int* in_sizes, int n_in,
                              void* d_out, int out_size, void* d_ws, size_t ws_size,
                              hipStream_t stream) {
    const float* X  = (const float*)d_in[0];
    const int*   ei = (const int*)d_in[1];   // int32 (jax x64 disabled)
    const float* W1 = (const float*)d_in[2];
    const float* b1 = (const float*)d_in[3];
    const float* W2 = (const float*)d_in[4];
    const float* b2 = (const float*)d_in[5];

    int N = in_sizes[0] / INF;  // 100000
    int E = in_sizes[1] / 2;    // 1600000
    const int* srcA = ei;
    const int* dstA = ei + E;

    int nt  = (E + TILE_E - 1) / TILE_E;  // 98 tiles
    int nbk = (N + 1023) >> 10;           // 98 buckets

    // workspace layout (16B-aligned head first)
    uint4*    Xs4      = (uint4*)d_ws;                     // N*8 = 12.8 MB
    unsigned* binned   = (unsigned*)(Xs4 + (size_t)N * 8); // E
    int*      eSrc     = (int*)(binned + E);               // E
    _Float16* W1t      = (_Float16*)(eSrc + E);            // HID*INF = 16 KB
    int*      tileCnt  = (int*)(W1t + HID * INF);          // nt*MAXBK
    int*      tileBase = tileCnt + nt * MAXBK;             // nt*MAXBK
    int*      bBase    = tileBase + nt * MAXBK;            // nbk+1
    int*      rowPtr   = bBase + nbk + 1;                  // N+1
    float*    dinv     = (float*)(rowPtr + N + 1);         // N
    float*    svs      = dinv + N;                         // N
    float*    out      = (float*)d_out;

    int gridB = max(nt, nbk);  // 98
    const float4* X4c = (const float4*)X;
    void* args[] = {
        (void*)&srcA, (void*)&dstA, (void*)&X4c, (void*)&W1,
        (void*)&tileCnt, (void*)&tileBase, (void*)&bBase, (void*)&rowPtr,
        (void*)&dinv, (void*)&binned, (void*)&eSrc, (void*)&Xs4,
        (void*)&W1t, (void*)&N, (void*)&E, (void*)&nt, (void*)&nbk
    };
    hipLaunchCooperativeKernel((const void*)k_build, dim3(gridB), dim3(1024),
                               args, 0, stream);

    k_agg_mlp<<<(N + 31) / 32, 256, 0, stream>>>(Xs4, rowPtr, eSrc, dinv,
                                                 (const uint4*)W1t, b1, W2, svs, N);
    k_out<<<(N * 16 + 255) / 256, 256, 0, stream>>>(rowPtr, eSrc, dinv, svs, b2, out, N);
}

// Round 12
// 113.104 us; speedup vs baseline: 1.5225x; 1.5225x over previous
//
#include <hip/hip_runtime.h>
#include <hip/hip_fp16.h>

// GCN 2-layer forward — f16 CSR-gather fused with MFMA MLP.
// CSR build: 2-level LDS-staged counting sort. 5 launches total:
//   k_thist (+W1t prep in extra block) -> k_bscan -> k_bin ->
//   k_csr (counting sort + fused prescale of own bucket) ->
//   k_agg_mlp (gather + MFMA MLP) -> k_out.
// Algebra: A_hat(X@W1)=(A_hat X)@W1 with Xs=f16(dinv*X); CSR records src-only;
// layer 2 via svs = dinv * dot(relu(agg@W1+b1), W2), scalar gather + b2.

#define NNODES 100000
#define INF 64
#define HID 128
#define MAXBK 128     // max buckets (1024 nodes each)
#define TILE_E 16384  // edges per binning tile (1024 thr x 16)

using half8 = __attribute__((ext_vector_type(8))) _Float16;
using f32x4 = __attribute__((ext_vector_type(4))) float;

// A1: per-tile per-bucket histogram; extra block (bx==nt) builds W1t = f16(W1^T)
__global__ __launch_bounds__(1024) void k_thist(const int* __restrict__ dstA,
                                                int* __restrict__ tileCnt, int nE,
                                                const float* __restrict__ W1,
                                                _Float16* __restrict__ W1t, int nt) {
    __shared__ int h[MAXBK];
    int tid = threadIdx.x;
    int bx = blockIdx.x;
    if (bx == nt) {  // W1t[n][k] = W1[k][n]
        for (int i = tid; i < HID * INF; i += 1024) {
            int nCol = i >> 6;
            int k = i & 63;
            W1t[i] = (_Float16)W1[k * HID + nCol];
        }
        return;
    }
    if (tid < MAXBK) h[tid] = 0;
    __syncthreads();
    int base = bx * TILE_E;
#pragma unroll
    for (int k = 0; k < 16; ++k) {
        int e = base + k * 1024 + tid;
        if (e < nE) atomicAdd(&h[((unsigned)dstA[e]) >> 10], 1);
    }
    __syncthreads();
    if (tid < MAXBK) tileCnt[bx * MAXBK + tid] = h[tid];
}

// A2: bucket-major scan (parallel: 8 tile-chunks x 128 buckets)
__global__ __launch_bounds__(1024) void k_bscan(const int* __restrict__ tileCnt,
                                                int* __restrict__ tileBase,
                                                int* __restrict__ bBase,
                                                int* __restrict__ rowPtr,
                                                int n, int nbk, int nt) {
    __shared__ int part[8][MAXBK];
    __shared__ int colScan[MAXBK];
    int b = threadIdx.x & (MAXBK - 1);
    int tg = threadIdx.x >> 7;               // 0..7
    int cpg = (nt + 7) / 8;
    int tlo = tg * cpg, thi = min(tlo + cpg, nt);
    int sum = 0;
    for (int t = tlo; t < thi; ++t) sum += tileCnt[t * MAXBK + b];
    part[tg][b] = sum;
    __syncthreads();
    int coff = 0;
    for (int g = 0; g < tg; ++g) coff += part[g][b];
    int ctot = 0;
#pragma unroll
    for (int g = 0; g < 8; ++g) ctot += part[g][b];
    if (tg == 0) colScan[b] = ctot;
    __syncthreads();
    for (int off = 1; off < MAXBK; off <<= 1) {
        int u = (tg == 0 && b >= off) ? colScan[b - off] : 0;
        __syncthreads();
        if (tg == 0) colScan[b] += u;
        __syncthreads();
    }
    int colBase = colScan[b] - ctot;
    if (tg == 0 && b < nbk) bBase[b] = colBase;
    if (tg == 0 && b == nbk - 1) { bBase[nbk] = colScan[b]; rowPtr[n] = colScan[b]; }
    int run = colBase + coff;
    for (int t = tlo; t < thi; ++t) {
        tileBase[t * MAXBK + b] = run;
        run += tileCnt[t * MAXBK + b];
    }
}

// A3: binning scatter; writes dense per-(tile,bucket) runs (no amplification)
__global__ __launch_bounds__(1024) void k_bin(const int* __restrict__ srcA,
                                              const int* __restrict__ dstA,
                                              const int* __restrict__ tileBase,
                                              unsigned* __restrict__ binned, int nE) {
    __shared__ int myb[MAXBK];
    __shared__ int cur[MAXBK];
    int tid = threadIdx.x;
    if (tid < MAXBK) {
        myb[tid] = tileBase[blockIdx.x * MAXBK + tid];
        cur[tid] = 0;
    }
    __syncthreads();
    int base = blockIdx.x * TILE_E;
#pragma unroll
    for (int k = 0; k < 16; ++k) {
        int e = base + k * 1024 + tid;
        if (e < nE) {
            int d = dstA[e];
            int s = srcA[e];
            int bk = ((unsigned)d) >> 10;
            int off = atomicAdd(&cur[bk], 1);
            binned[myb[bk] + off] = ((unsigned)(d & 1023) << 17) | (unsigned)s;
        }
    }
}

// B: per-bucket counting sort -> rowPtr, dinv, eSrc; then fused prescale of
// this bucket's 1024 nodes: Xs = f16(dinv * X) (dD cached in LDS, coalesced).
__global__ __launch_bounds__(1024) void k_csr(const unsigned* __restrict__ binned,
                                              const int* __restrict__ bBase,
                                              int* __restrict__ rowPtr,
                                              float* __restrict__ dinv,
                                              int* __restrict__ eSrc,
                                              const float4* __restrict__ X4,
                                              uint4* __restrict__ Xs4, int n) {
    __shared__ int hist[1024];
    __shared__ int curs[1024];
    int tid = threadIdx.x;
    int b = blockIdx.x;
    int lo = bBase[b], hi = bBase[b + 1];
    hist[tid] = 0;
    __syncthreads();
    for (int i = lo + tid; i < hi; i += 1024)
        atomicAdd(&hist[binned[i] >> 17], 1);
    __syncthreads();
    int own = hist[tid];
    for (int off = 1; off < 1024; off <<= 1) {
        int u = (tid >= off) ? hist[tid - off] : 0;
        __syncthreads();
        hist[tid] += u;
        __syncthreads();
    }
    int pos0 = lo + hist[tid] - own;
    curs[tid] = pos0;
    float dD = rsqrtf((float)(own + 1));  // +1 self loop
    hist[tid] = (int)__float_as_uint(dD); // hist no longer needed: cache dD
    int node = (b << 10) + tid;
    if (node < n) {
        rowPtr[node] = pos0;
        dinv[node] = dD;
    }
    __syncthreads();
    for (int i = lo + tid; i < hi; i += 1024) {
        unsigned v = binned[i];
        int pos = atomicAdd(&curs[v >> 17], 1);
        eSrc[pos] = (int)(v & 0x1FFFFu);
    }
    __syncthreads();
    // fused prescale: 8192 (node,chunk) items, coalesced
    int nbase = b << 10;
#pragma unroll
    for (int k2 = 0; k2 < 8; ++k2) {
        int t2 = k2 * 1024 + tid;
        int nl = t2 >> 3;
        int r2 = t2 & 7;
        int node2 = nbase + nl;
        if (node2 < n) {
            float dD2 = __uint_as_float((unsigned)hist[nl]);
            float4 a = X4[(size_t)node2 * 16 + r2 * 2];
            float4 bb = X4[(size_t)node2 * 16 + r2 * 2 + 1];
            __half2 h0 = __float22half2_rn(make_float2(dD2 * a.x, dD2 * a.y));
            __half2 h1 = __float22half2_rn(make_float2(dD2 * a.z, dD2 * a.w));
            __half2 h2 = __float22half2_rn(make_float2(dD2 * bb.x, dD2 * bb.y));
            __half2 h3 = __float22half2_rn(make_float2(dD2 * bb.z, dD2 * bb.w));
            uint4 o;
            o.x = *(unsigned*)&h0; o.y = *(unsigned*)&h1;
            o.z = *(unsigned*)&h2; o.w = *(unsigned*)&h3;
            Xs4[(size_t)node2 * 8 + r2] = o;
        }
    }
}

__device__ inline void acc8_add(const uint4& v, float* acc) {
    const __half2* hp = (const __half2*)&v;
#pragma unroll
    for (int i = 0; i < 4; ++i) {
        float2 f = __half22float2(hp[i]);
        acc[2 * i]     += f.x;
        acc[2 * i + 1] += f.y;
    }
}

// Fused gather + MFMA MLP. 256 thr = 32 nodes/block.
// Phase 1: 8 lanes/node gather agg row (f32 acc, 8 rows in flight) ->
//          f16 row in swizzled LDS.
// Phase 2: waves 0-1 each run one 16-node MFMA tile (8 N-tiles x 2 K-steps),
//          A/B frags from LDS; epilogue bias+relu+W2-dot; svs = dinv*result.
__global__ __launch_bounds__(256) void k_agg_mlp(const uint4* __restrict__ Xs4,
                                                 const int* __restrict__ rowPtr,
                                                 const int* __restrict__ eSrc,
                                                 const float* __restrict__ dinv,
                                                 const uint4* __restrict__ W1t4,
                                                 const float* __restrict__ b1,
                                                 const float* __restrict__ W2,
                                                 float* __restrict__ svs, int n) {
    __shared__ __align__(16) unsigned short W1s[HID * INF];  // 16 KB swizzled
    __shared__ __align__(16) unsigned short aggS[32 * INF];  // 4 KB swizzled
    __shared__ float b1s[HID];
    __shared__ float W2s[HID];
    int tid = threadIdx.x;

    // phase 0: stage W1t into swizzled LDS (+ bias/W2)
    for (int i = tid; i < HID * 8; i += 256) {   // 1024 uint4 chunks
        int c = i >> 3, cb = i & 7;
        uint4 v = W1t4[i];
        int off = c * 128 + ((cb * 16) ^ ((c & 7) << 4));
        *(uint4*)((char*)W1s + off) = v;
    }
    if (tid < HID) {
        b1s[tid] = b1[tid];
        W2s[tid] = W2[tid];
    }

    // phase 1: gather
    int node0 = blockIdx.x * 32;
    int w = tid >> 3;   // local node 0..31
    int r = tid & 7;    // 16B chunk of the 128B row
    int node = node0 + w;
    if (node < n) {
        int beg = rowPtr[node];
        int end = rowPtr[node + 1];
        float dD = dinv[node];
        float acc[8];
        {   // self-loop init
            uint4 v = Xs4[(size_t)node * 8 + r];
            const __half2* hp = (const __half2*)&v;
#pragma unroll
            for (int i = 0; i < 4; ++i) {
                float2 f = __half22float2(hp[i]);
                acc[2 * i] = f.x;
                acc[2 * i + 1] = f.y;
            }
        }
        int j = beg;
        int aEnd = min(end, (beg + 3) & ~3);
        for (; j < aEnd; ++j) {
            uint4 v = Xs4[(size_t)eSrc[j] * 8 + r];
            acc8_add(v, acc);
        }
        for (; j + 7 < end; j += 8) {   // 8 rows in flight
            int4 sa = *(const int4*)(eSrc + j);
            int4 sb = *(const int4*)(eSrc + j + 4);
            uint4 v0 = Xs4[(size_t)sa.x * 8 + r];
            uint4 v1 = Xs4[(size_t)sa.y * 8 + r];
            uint4 v2 = Xs4[(size_t)sa.z * 8 + r];
            uint4 v3 = Xs4[(size_t)sa.w * 8 + r];
            uint4 v4 = Xs4[(size_t)sb.x * 8 + r];
            uint4 v5 = Xs4[(size_t)sb.y * 8 + r];
            uint4 v6 = Xs4[(size_t)sb.z * 8 + r];
            uint4 v7 = Xs4[(size_t)sb.w * 8 + r];
            acc8_add(v0, acc); acc8_add(v1, acc); acc8_add(v2, acc); acc8_add(v3, acc);
            acc8_add(v4, acc); acc8_add(v5, acc); acc8_add(v6, acc); acc8_add(v7, acc);
        }
        if (j + 3 < end) {
            int4 s4 = *(const int4*)(eSrc + j);
            uint4 v0 = Xs4[(size_t)s4.x * 8 + r];
            uint4 v1 = Xs4[(size_t)s4.y * 8 + r];
            uint4 v2 = Xs4[(size_t)s4.z * 8 + r];
            uint4 v3 = Xs4[(size_t)s4.w * 8 + r];
            acc8_add(v0, acc); acc8_add(v1, acc); acc8_add(v2, acc); acc8_add(v3, acc);
            j += 4;
        }
        for (; j < end; ++j) {
            uint4 v = Xs4[(size_t)eSrc[j] * 8 + r];
            acc8_add(v, acc);
        }
        __half2 h0 = __float22half2_rn(make_float2(dD * acc[0], dD * acc[1]));
        __half2 h1 = __float22half2_rn(make_float2(dD * acc[2], dD * acc[3]));
        __half2 h2 = __float22half2_rn(make_float2(dD * acc[4], dD * acc[5]));
        __half2 h3 = __float22half2_rn(make_float2(dD * acc[6], dD * acc[7]));
        uint4 o;
        o.x = *(unsigned*)&h0; o.y = *(unsigned*)&h1;
        o.z = *(unsigned*)&h2; o.w = *(unsigned*)&h3;
        int off = w * 128 + ((r * 16) ^ ((w & 7) << 4));
        *(uint4*)((char*)aggS + off) = o;
    }
    __syncthreads();

    // phase 2: MFMA (waves 0-1)
    int wave = tid >> 6;
    if (wave < 2) {
        int l = tid & 63;
        int row16 = l & 15;
        int kg = l >> 4;
        int lrow = wave * 16 + row16;
        int swzA = (lrow & 7) << 4;
        half8 a0 = *(const half8*)((const char*)aggS + lrow * 128 + ((kg * 16) ^ swzA));
        half8 a1 = *(const half8*)((const char*)aggS + lrow * 128 + ((64 + kg * 16) ^ swzA));
        float p0 = 0.0f, p1 = 0.0f, p2 = 0.0f, p3 = 0.0f;
#pragma unroll
        for (int nt = 0; nt < 8; ++nt) {
            int c = nt * 16 + row16;
            int swzB = (c & 7) << 4;
            half8 bf0 = *(const half8*)((const char*)W1s + c * 128 + ((kg * 16) ^ swzB));
            half8 bf1 = *(const half8*)((const char*)W1s + c * 128 + ((64 + kg * 16) ^ swzB));
            f32x4 acc4 = {0.0f, 0.0f, 0.0f, 0.0f};
            acc4 = __builtin_amdgcn_mfma_f32_16x16x32_f16(a0, bf0, acc4, 0, 0, 0);
            acc4 = __builtin_amdgcn_mfma_f32_16x16x32_f16(a1, bf1, acc4, 0, 0, 0);
            float b1v = b1s[c];
            float w2v = W2s[c];
            float h;
            h = fmaxf(acc4[0] + b1v, 0.0f); p0 = fmaf(h, w2v, p0);
            h = fmaxf(acc4[1] + b1v, 0.0f); p1 = fmaf(h, w2v, p1);
            h = fmaxf(acc4[2] + b1v, 0.0f); p2 = fmaf(h, w2v, p2);
            h = fmaxf(acc4[3] + b1v, 0.0f); p3 = fmaf(h, w2v, p3);
        }
#pragma unroll
        for (int off = 1; off < 16; off <<= 1) {
            p0 += __shfl_xor(p0, off, 64);
            p1 += __shfl_xor(p1, off, 64);
            p2 += __shfl_xor(p2, off, 64);
            p3 += __shfl_xor(p3, off, 64);
        }
        if (row16 == 0) {
            int nd = node0 + wave * 16 + kg * 4;
            if (nd + 0 < n) svs[nd + 0] = dinv[nd + 0] * p0;
            if (nd + 1 < n) svs[nd + 1] = dinv[nd + 1] * p1;
            if (nd + 2 < n) svs[nd + 2] = dinv[nd + 2] * p2;
            if (nd + 3 < n) svs[nd + 3] = dinv[nd + 3] * p3;
        }
    }
}

// 4 nodes per wave: out[d] = dD*(sum svs[src] + svs[d]) + b2
__global__ __launch_bounds__(256) void k_out(const int* __restrict__ rowPtr,
                                             const int* __restrict__ eSrc,
                                             const float* __restrict__ dinv,
                                             const float* __restrict__ svs,
                                             const float* __restrict__ b2,
                                             float* __restrict__ out, int n) {
    int t = blockIdx.x * blockDim.x + threadIdx.x;
    int node = t >> 4;
    int r = t & 15;
    if (node >= n) return;
    int beg = rowPtr[node];
    int end = rowPtr[node + 1];
    float p = 0.0f;
    for (int j = beg + r; j < end; j += 16) p += svs[eSrc[j]];
    p += __shfl_xor(p, 1, 16);
    p += __shfl_xor(p, 2, 16);
    p += __shfl_xor(p, 4, 16);
    p += __shfl_xor(p, 8, 16);
    if (r == 0) {
        float dD = dinv[node];
        out[node] = fmaf(dD, p + svs[node], b2[0]);
    }
}

extern "C" void kernel_launch(void* const* d_in, const int* in_sizes, int n_in,
                              void* d_out, int out_size, void* d_ws, size_t ws_size,
                              hipStream_t stream) {
    const float* X  = (const float*)d_in[0];
    const int*   ei = (const int*)d_in[1];   // int32 (jax x64 disabled)
    const float* W1 = (const float*)d_in[2];
    const float* b1 = (const float*)d_in[3];
    const float* W2 = (const float*)d_in[4];
    const float* b2 = (const float*)d_in[5];

    int N = in_sizes[0] / INF;  // 100000
    int E = in_sizes[1] / 2;    // 1600000
    const int* srcA = ei;
    const int* dstA = ei + E;

    int nt  = (E + TILE_E - 1) / TILE_E;  // 98 tiles
    int nbk = (N + 1023) >> 10;           // 98 buckets

    // workspace layout (16B-aligned head first)
    uint4*    Xs4      = (uint4*)d_ws;                     // N*8 = 12.8 MB
    unsigned* binned   = (unsigned*)(Xs4 + (size_t)N * 8); // E
    int*      eSrc     = (int*)(binned + E);               // E
    _Float16* W1t      = (_Float16*)(eSrc + E);            // HID*INF = 16 KB
    int*      tileCnt  = (int*)(W1t + HID * INF);          // nt*MAXBK
    int*      tileBase = tileCnt + nt * MAXBK;             // nt*MAXBK
    int*      bBase    = tileBase + nt * MAXBK;            // nbk+1
    int*      rowPtr   = bBase + nbk + 1;                  // N+1
    float*    dinv     = (float*)(rowPtr + N + 1);         // N
    float*    svs      = dinv + N;                         // N
    float*    out      = (float*)d_out;

    k_thist<<<nt + 1, 1024, 0, stream>>>(dstA, tileCnt, E, W1, W1t, nt);
    k_bscan<<<1, 1024, 0, stream>>>(tileCnt, tileBase, bBase, rowPtr, N, nbk, nt);
    k_bin<<<nt, 1024, 0, stream>>>(srcA, dstA, tileBase, binned, E);
    k_csr<<<nbk, 1024, 0, stream>>>(binned, bBase, rowPtr, dinv, eSrc,
                                    (const float4*)X, Xs4, N);
    k_agg_mlp<<<(N + 31) / 32, 256, 0, stream>>>(Xs4, rowPtr, eSrc, dinv,
                                                 (const uint4*)W1t, b1, W2, svs, N);
    k_out<<<(N * 16 + 255) / 256, 256, 0, stream>>>(rowPtr, eSrc, dinv, svs, b2, out, N);
}

// Round 13
// 93.520 us; speedup vs baseline: 1.8414x; 1.2094x over previous
//
#include <hip/hip_runtime.h>
#include <hip/hip_fp16.h>

// GCN 2-layer forward — f16 CSR-gather fused with MFMA MLP. 4 launches:
//  k_histbin: per-tile (8K edges) hist over 196 buckets(512 nodes) + LDS scan
//             -> tileOff[t][b]; scatter reg-held edges to tile-major binned.
//  k_csr:     per-bucket; global base = sum_t tileOff[t][b] (self-contained);
//             segmented edge reads, counting sort -> rowPtr/dinv/eSrc; fused
//             prescale Xs = f16(dinv*X) of own 512 nodes.
//  k_agg_mlp: 32 nodes/block gather (8 rows in flight) -> swizzled LDS ->
//             16x16x32_f16 MFMA MLP -> svs = dinv*dot(relu(agg@W1+b1),W2).
//  k_out:     scalar CSR gather: out = dD*(sum svs[src]+svs[d]) + b2.

#define INF 64
#define HID 128
#define BKBITS 9
#define BKSZ 512      // nodes per bucket
#define TILE_E 8192   // edges per tile (1024 thr x 8)
#define TOW 257       // tileOff row width

using half8 = __attribute__((ext_vector_type(8))) _Float16;
using f32x4 = __attribute__((ext_vector_type(4))) float;

// Per-tile histogram + in-LDS scan + scatter. Extra block (bx==nt): W1t prep.
__global__ __launch_bounds__(1024) void k_histbin(const int* __restrict__ srcA,
                                                  const int* __restrict__ dstA,
                                                  int* __restrict__ tileOff,
                                                  unsigned* __restrict__ binned,
                                                  int nE, int nt,
                                                  const float* __restrict__ W1,
                                                  _Float16* __restrict__ W1t) {
    int tid = threadIdx.x;
    int bx = blockIdx.x;
    if (bx == nt) {  // W1t[n][k] = f16(W1[k][n])
        for (int i = tid; i < HID * INF; i += 1024) {
            int nCol = i >> 6;
            int k = i & 63;
            W1t[i] = (_Float16)W1[k * HID + nCol];
        }
        return;
    }
    __shared__ int hist[256];
    __shared__ int curs[256];
    if (tid < 256) hist[tid] = 0;
    __syncthreads();
    int base = bx * TILE_E;
    int d[8], s[8];
#pragma unroll
    for (int k = 0; k < 8; ++k) {
        int e = base + k * 1024 + tid;
        if (e < nE) {
            d[k] = dstA[e];
            s[k] = srcA[e];
            atomicAdd(&hist[((unsigned)d[k]) >> BKBITS], 1);
        } else {
            d[k] = -1;
        }
    }
    __syncthreads();
    int own = (tid < 256) ? hist[tid] : 0;
    for (int off = 1; off < 256; off <<= 1) {  // inclusive scan, 8 rounds
        int u = (tid < 256 && tid >= off) ? hist[tid - off] : 0;
        __syncthreads();
        if (tid < 256) hist[tid] += u;
        __syncthreads();
    }
    if (tid < 256) {
        int ex = hist[tid] - own;
        curs[tid] = ex;
        tileOff[bx * TOW + tid] = ex;
        if (tid == 255) tileOff[bx * TOW + 256] = hist[255];  // tile total
    }
    __syncthreads();
#pragma unroll
    for (int k = 0; k < 8; ++k) {
        if (d[k] >= 0) {
            int bk = ((unsigned)d[k]) >> BKBITS;
            int off = atomicAdd(&curs[bk], 1);
            binned[base + off] = ((unsigned)(d[k] & (BKSZ - 1)) << 17) | (unsigned)s[k];
        }
    }
}

// Per-bucket counting sort + fused prescale. Self-contained global base.
__global__ __launch_bounds__(1024) void k_csr(const unsigned* __restrict__ binned,
                                              const int* __restrict__ tileOff,
                                              int* __restrict__ rowPtr,
                                              float* __restrict__ dinv,
                                              int* __restrict__ eSrc,
                                              const float4* __restrict__ X4,
                                              uint4* __restrict__ Xs4,
                                              int n, int nt, int nbk) {
    __shared__ int segS[256], segL[256];
    __shared__ int hist[512];
    __shared__ int curs[512];
    __shared__ float ddv[512];
    __shared__ int bBaseS;
    int tid = threadIdx.x;
    int b = blockIdx.x;
    if (tid == 0) bBaseS = 0;
    if (tid < 512) hist[tid] = 0;
    __syncthreads();
    if (tid < nt) {
        int o0 = tileOff[tid * TOW + b];
        int o1 = tileOff[tid * TOW + b + 1];
        segS[tid] = tid * TILE_E + o0;
        segL[tid] = o1 - o0;
        atomicAdd(&bBaseS, o0);  // sum of per-tile excl prefixes = global base
    }
    __syncthreads();
    int w = tid >> 6, lane = tid & 63;
    for (int t = w; t < nt; t += 16)
        for (int l = lane; l < segL[t]; l += 64)
            atomicAdd(&hist[binned[segS[t] + l] >> 17], 1);
    __syncthreads();
    int own = (tid < 512) ? hist[tid] : 0;
    for (int off = 1; off < 512; off <<= 1) {  // inclusive scan, 9 rounds
        int u = (tid < 512 && tid >= off) ? hist[tid - off] : 0;
        __syncthreads();
        if (tid < 512) hist[tid] += u;
        __syncthreads();
    }
    int bBase = bBaseS;
    if (tid < 512) {
        int pos0 = bBase + hist[tid] - own;
        curs[tid] = pos0;
        float dD = rsqrtf((float)(own + 1));  // +1 self loop
        ddv[tid] = dD;
        int node = (b << BKBITS) + tid;
        if (node < n) {
            rowPtr[node] = pos0;
            dinv[node] = dD;
        }
        if (b == nbk - 1 && tid == 511) rowPtr[n] = bBase + hist[511];
    }
    __syncthreads();
    for (int t = w; t < nt; t += 16)
        for (int l = lane; l < segL[t]; l += 64) {
            unsigned v = binned[segS[t] + l];
            int pos = atomicAdd(&curs[v >> 17], 1);
            eSrc[pos] = (int)(v & 0x1FFFFu);
        }
    // fused prescale of this bucket's nodes (no barrier needed: ddv ready)
    int nbase = b << BKBITS;
#pragma unroll
    for (int k2 = 0; k2 < 4; ++k2) {
        int t2 = k2 * 1024 + tid;
        int nl = t2 >> 3;
        int r2 = t2 & 7;
        int node2 = nbase + nl;
        if (node2 < n) {
            float dD2 = ddv[nl];
            float4 a = X4[(size_t)node2 * 16 + r2 * 2];
            float4 bb = X4[(size_t)node2 * 16 + r2 * 2 + 1];
            __half2 h0 = __float22half2_rn(make_float2(dD2 * a.x, dD2 * a.y));
            __half2 h1 = __float22half2_rn(make_float2(dD2 * a.z, dD2 * a.w));
            __half2 h2 = __float22half2_rn(make_float2(dD2 * bb.x, dD2 * bb.y));
            __half2 h3 = __float22half2_rn(make_float2(dD2 * bb.z, dD2 * bb.w));
            uint4 o;
            o.x = *(unsigned*)&h0; o.y = *(unsigned*)&h1;
            o.z = *(unsigned*)&h2; o.w = *(unsigned*)&h3;
            Xs4[(size_t)node2 * 8 + r2] = o;
        }
    }
}

__device__ inline void acc8_add(const uint4& v, float* acc) {
    const __half2* hp = (const __half2*)&v;
#pragma unroll
    for (int i = 0; i < 4; ++i) {
        float2 f = __half22float2(hp[i]);
        acc[2 * i]     += f.x;
        acc[2 * i + 1] += f.y;
    }
}

// Fused gather + MFMA MLP. 256 thr = 32 nodes/block.
__global__ __launch_bounds__(256) void k_agg_mlp(const uint4* __restrict__ Xs4,
                                                 const int* __restrict__ rowPtr,
                                                 const int* __restrict__ eSrc,
                                                 const float* __restrict__ dinv,
                                                 const uint4* __restrict__ W1t4,
                                                 const float* __restrict__ b1,
                                                 const float* __restrict__ W2,
                                                 float* __restrict__ svs, int n) {
    __shared__ __align__(16) unsigned short W1s[HID * INF];  // 16 KB swizzled
    __shared__ __align__(16) unsigned short aggS[32 * INF];  // 4 KB swizzled
    __shared__ float b1s[HID];
    __shared__ float W2s[HID];
    int tid = threadIdx.x;

    for (int i = tid; i < HID * 8; i += 256) {   // stage W1t swizzled
        int c = i >> 3, cb = i & 7;
        uint4 v = W1t4[i];
        int off = c * 128 + ((cb * 16) ^ ((c & 7) << 4));
        *(uint4*)((char*)W1s + off) = v;
    }
    if (tid < HID) {
        b1s[tid] = b1[tid];
        W2s[tid] = W2[tid];
    }

    int node0 = blockIdx.x * 32;
    int w = tid >> 3;
    int r = tid & 7;
    int node = node0 + w;
    if (node < n) {
        int beg = rowPtr[node];
        int end = rowPtr[node + 1];
        float dD = dinv[node];
        float acc[8];
        {
            uint4 v = Xs4[(size_t)node * 8 + r];
            const __half2* hp = (const __half2*)&v;
#pragma unroll
            for (int i = 0; i < 4; ++i) {
                float2 f = __half22float2(hp[i]);
                acc[2 * i] = f.x;
                acc[2 * i + 1] = f.y;
            }
        }
        int j = beg;
        int aEnd = min(end, (beg + 3) & ~3);
        for (; j < aEnd; ++j) {
            uint4 v = Xs4[(size_t)eSrc[j] * 8 + r];
            acc8_add(v, acc);
        }
        for (; j + 7 < end; j += 8) {
            int4 sa = *(const int4*)(eSrc + j);
            int4 sb = *(const int4*)(eSrc + j + 4);
            uint4 v0 = Xs4[(size_t)sa.x * 8 + r];
            uint4 v1 = Xs4[(size_t)sa.y * 8 + r];
            uint4 v2 = Xs4[(size_t)sa.z * 8 + r];
            uint4 v3 = Xs4[(size_t)sa.w * 8 + r];
            uint4 v4 = Xs4[(size_t)sb.x * 8 + r];
            uint4 v5 = Xs4[(size_t)sb.y * 8 + r];
            uint4 v6 = Xs4[(size_t)sb.z * 8 + r];
            uint4 v7 = Xs4[(size_t)sb.w * 8 + r];
            acc8_add(v0, acc); acc8_add(v1, acc); acc8_add(v2, acc); acc8_add(v3, acc);
            acc8_add(v4, acc); acc8_add(v5, acc); acc8_add(v6, acc); acc8_add(v7, acc);
        }
        if (j + 3 < end) {
            int4 s4 = *(const int4*)(eSrc + j);
            uint4 v0 = Xs4[(size_t)s4.x * 8 + r];
            uint4 v1 = Xs4[(size_t)s4.y * 8 + r];
            uint4 v2 = Xs4[(size_t)s4.z * 8 + r];
            uint4 v3 = Xs4[(size_t)s4.w * 8 + r];
            acc8_add(v0, acc); acc8_add(v1, acc); acc8_add(v2, acc); acc8_add(v3, acc);
            j += 4;
        }
        for (; j < end; ++j) {
            uint4 v = Xs4[(size_t)eSrc[j] * 8 + r];
            acc8_add(v, acc);
        }
        __half2 h0 = __float22half2_rn(make_float2(dD * acc[0], dD * acc[1]));
        __half2 h1 = __float22half2_rn(make_float2(dD * acc[2], dD * acc[3]));
        __half2 h2 = __float22half2_rn(make_float2(dD * acc[4], dD * acc[5]));
        __half2 h3 = __float22half2_rn(make_float2(dD * acc[6], dD * acc[7]));
        uint4 o;
        o.x = *(unsigned*)&h0; o.y = *(unsigned*)&h1;
        o.z = *(unsigned*)&h2; o.w = *(unsigned*)&h3;
        int off = w * 128 + ((r * 16) ^ ((w & 7) << 4));
        *(uint4*)((char*)aggS + off) = o;
    }
    __syncthreads();

    int wave = tid >> 6;
    if (wave < 2) {
        int l = tid & 63;
        int row16 = l & 15;
        int kg = l >> 4;
        int lrow = wave * 16 + row16;
        int swzA = (lrow & 7) << 4;
        half8 a0 = *(const half8*)((const char*)aggS + lrow * 128 + ((kg * 16) ^ swzA));
        half8 a1 = *(const half8*)((const char*)aggS + lrow * 128 + ((64 + kg * 16) ^ swzA));
        float p0 = 0.0f, p1 = 0.0f, p2 = 0.0f, p3 = 0.0f;
#pragma unroll
        for (int nt = 0; nt < 8; ++nt) {
            int c = nt * 16 + row16;
            int swzB = (c & 7) << 4;
            half8 bf0 = *(const half8*)((const char*)W1s + c * 128 + ((kg * 16) ^ swzB));
            half8 bf1 = *(const half8*)((const char*)W1s + c * 128 + ((64 + kg * 16) ^ swzB));
            f32x4 acc4 = {0.0f, 0.0f, 0.0f, 0.0f};
            acc4 = __builtin_amdgcn_mfma_f32_16x16x32_f16(a0, bf0, acc4, 0, 0, 0);
            acc4 = __builtin_amdgcn_mfma_f32_16x16x32_f16(a1, bf1, acc4, 0, 0, 0);
            float b1v = b1s[c];
            float w2v = W2s[c];
            float h;
            h = fmaxf(acc4[0] + b1v, 0.0f); p0 = fmaf(h, w2v, p0);
            h = fmaxf(acc4[1] + b1v, 0.0f); p1 = fmaf(h, w2v, p1);
            h = fmaxf(acc4[2] + b1v, 0.0f); p2 = fmaf(h, w2v, p2);
            h = fmaxf(acc4[3] + b1v, 0.0f); p3 = fmaf(h, w2v, p3);
        }
#pragma unroll
        for (int off = 1; off < 16; off <<= 1) {
            p0 += __shfl_xor(p0, off, 64);
            p1 += __shfl_xor(p1, off, 64);
            p2 += __shfl_xor(p2, off, 64);
            p3 += __shfl_xor(p3, off, 64);
        }
        if (row16 == 0) {
            int nd = node0 + wave * 16 + kg * 4;
            if (nd + 0 < n) svs[nd + 0] = dinv[nd + 0] * p0;
            if (nd + 1 < n) svs[nd + 1] = dinv[nd + 1] * p1;
            if (nd + 2 < n) svs[nd + 2] = dinv[nd + 2] * p2;
            if (nd + 3 < n) svs[nd + 3] = dinv[nd + 3] * p3;
        }
    }
}

// 4 nodes per wave: out[d] = dD*(sum svs[src] + svs[d]) + b2
__global__ __launch_bounds__(256) void k_out(const int* __restrict__ rowPtr,
                                             const int* __restrict__ eSrc,
                                             const float* __restrict__ dinv,
                                             const float* __restrict__ svs,
                                             const float* __restrict__ b2,
                                             float* __restrict__ out, int n) {
    int t = blockIdx.x * blockDim.x + threadIdx.x;
    int node = t >> 4;
    int r = t & 15;
    if (node >= n) return;
    int beg = rowPtr[node];
    int end = rowPtr[node + 1];
    float p = 0.0f;
    for (int j = beg + r; j < end; j += 16) p += svs[eSrc[j]];
    p += __shfl_xor(p, 1, 16);
    p += __shfl_xor(p, 2, 16);
    p += __shfl_xor(p, 4, 16);
    p += __shfl_xor(p, 8, 16);
    if (r == 0) {
        float dD = dinv[node];
        out[node] = fmaf(dD, p + svs[node], b2[0]);
    }
}

extern "C" void kernel_launch(void* const* d_in, const int* in_sizes, int n_in,
                              void* d_out, int out_size, void* d_ws, size_t ws_size,
                              hipStream_t stream) {
    const float* X  = (const float*)d_in[0];
    const int*   ei = (const int*)d_in[1];   // int32 (jax x64 disabled)
    const float* W1 = (const float*)d_in[2];
    const float* b1 = (const float*)d_in[3];
    const float* W2 = (const float*)d_in[4];
    const float* b2 = (const float*)d_in[5];

    int N = in_sizes[0] / INF;  // 100000
    int E = in_sizes[1] / 2;    // 1600000
    const int* srcA = ei;
    const int* dstA = ei + E;

    int nt  = (E + TILE_E - 1) / TILE_E;       // 196 tiles
    int nbk = (N + BKSZ - 1) >> BKBITS;        // 196 buckets

    // workspace layout (16B-aligned head first)
    uint4*    Xs4      = (uint4*)d_ws;                     // N*8 = 12.8 MB
    unsigned* binned   = (unsigned*)(Xs4 + (size_t)N * 8); // nt*TILE_E
    int*      eSrc     = (int*)(binned + (size_t)nt * TILE_E);  // E
    _Float16* W1t      = (_Float16*)(eSrc + E);            // HID*INF
    int*      tileOff  = (int*)(W1t + HID * INF);          // nt*TOW
    int*      rowPtr   = tileOff + nt * TOW;               // N+1
    float*    dinv     = (float*)(rowPtr + N + 1);         // N
    float*    svs      = dinv + N;                         // N
    float*    out      = (float*)d_out;

    k_histbin<<<nt + 1, 1024, 0, stream>>>(srcA, dstA, tileOff, binned, E, nt, W1, W1t);
    k_csr<<<nbk, 1024, 0, stream>>>(binned, tileOff, rowPtr, dinv, eSrc,
                                    (const float4*)X, Xs4, N, nt, nbk);
    k_agg_mlp<<<(N + 31) / 32, 256, 0, stream>>>(Xs4, rowPtr, eSrc, dinv,
                                                 (const uint4*)W1t, b1, W2, svs, N);
    k_out<<<(N * 16 + 255) / 256, 256, 0, stream>>>(rowPtr, eSrc, dinv, svs, b2, out, N);
}